// Round 1
// baseline (16415.210 us; speedup 1.0000x reference)
//
#include <hip/hip_runtime.h>
#include <math.h>

#define B_SZ 4096
#define D_SZ 1024
#define H_SZ 1024
#define T_SZ 50

#define BM 64
#define BN 64
#define BK 16

typedef __attribute__((ext_vector_type(4))) float f4;

__device__ __forceinline__ float sigmoidf_(float x) {
    return 1.0f / (1.0f + expf(-x));
}

// h0 = tanh(ev @ w_init^T + b_init)   (B x H), K = D
__global__ __launch_bounds__(256) void h0_kernel(
        const float* __restrict__ ev, const float* __restrict__ w_init,
        const float* __restrict__ b_init, float* __restrict__ h0) {
    __shared__ __align__(16) float sA[BK][BM];
    __shared__ __align__(16) float sW[BK][BN];
    const int tid = threadIdx.x;
    const int tx = tid % 16, ty = tid / 16;
    const int b0 = blockIdx.y * BM, j0 = blockIdx.x * BN;
    const int lrow = tid / 4, lc4 = tid % 4;  // staging row / k-chunk

    float acc[4][4] = {};

    for (int k0 = 0; k0 < D_SZ; k0 += BK) {
        f4 a4 = *(const f4*)&ev[(b0 + lrow) * D_SZ + k0 + lc4 * 4];
        f4 w4 = *(const f4*)&w_init[(j0 + lrow) * D_SZ + k0 + lc4 * 4];
        __syncthreads();
#pragma unroll
        for (int c = 0; c < 4; ++c) {
            sA[lc4 * 4 + c][lrow] = a4[c];
            sW[lc4 * 4 + c][lrow] = w4[c];
        }
        __syncthreads();
#pragma unroll
        for (int kk = 0; kk < BK; ++kk) {
            f4 af = *(const f4*)&sA[kk][ty * 4];
            f4 wf = *(const f4*)&sW[kk][tx * 4];
#pragma unroll
            for (int i = 0; i < 4; ++i)
#pragma unroll
                for (int j = 0; j < 4; ++j)
                    acc[i][j] += af[i] * wf[j];
        }
    }

#pragma unroll
    for (int j = 0; j < 4; ++j) {
        int jj = j0 + tx * 4 + j;
        float bj = b_init[jj];
#pragma unroll
        for (int i = 0; i < 4; ++i) {
            int b = b0 + ty * 4 + i;
            h0[b * H_SZ + jj] = tanhf(acc[i][j] + bj);
        }
    }
}

// One GRU step: gh = h @ w_hh^T (3 gates), fused gate math, writes h_next.
// gx is computed inline (K=2 vs teacher prev).
__global__ __launch_bounds__(256) void step_kernel(
        const float* __restrict__ h, const float* __restrict__ w_hh,
        const float* __restrict__ b_hh, const float* __restrict__ w_ih,
        const float* __restrict__ b_ih, const float* __restrict__ teach,
        float* __restrict__ h_next, int t) {
    __shared__ __align__(16) float sA[BK][BM];
    __shared__ __align__(16) float sW[3][BK][BN];
    const int tid = threadIdx.x;
    const int tx = tid % 16, ty = tid / 16;
    const int b0 = blockIdx.y * BM, j0 = blockIdx.x * BN;
    const int lrow = tid / 4, lc4 = tid % 4;

    float acc[3][4][4] = {};

    for (int k0 = 0; k0 < H_SZ; k0 += BK) {
        f4 a4 = *(const f4*)&h[(b0 + lrow) * H_SZ + k0 + lc4 * 4];
        f4 w4[3];
#pragma unroll
        for (int g = 0; g < 3; ++g)
            w4[g] = *(const f4*)&w_hh[(g * H_SZ + j0 + lrow) * H_SZ + k0 + lc4 * 4];
        __syncthreads();
#pragma unroll
        for (int c = 0; c < 4; ++c) {
            sA[lc4 * 4 + c][lrow] = a4[c];
#pragma unroll
            for (int g = 0; g < 3; ++g)
                sW[g][lc4 * 4 + c][lrow] = w4[g][c];
        }
        __syncthreads();
#pragma unroll
        for (int kk = 0; kk < BK; ++kk) {
            f4 af = *(const f4*)&sA[kk][ty * 4];
            f4 wf0 = *(const f4*)&sW[0][kk][tx * 4];
            f4 wf1 = *(const f4*)&sW[1][kk][tx * 4];
            f4 wf2 = *(const f4*)&sW[2][kk][tx * 4];
#pragma unroll
            for (int i = 0; i < 4; ++i) {
#pragma unroll
                for (int j = 0; j < 4; ++j) {
                    acc[0][i][j] += af[i] * wf0[j];
                    acc[1][i][j] += af[i] * wf1[j];
                    acc[2][i][j] += af[i] * wf2[j];
                }
            }
        }
    }

    // prev deltas (teacher forcing; FREE_RATIO == 0 so prev = teach[t-1], 0 at t=0)
    float p0[4], p1[4];
#pragma unroll
    for (int i = 0; i < 4; ++i) {
        int b = b0 + ty * 4 + i;
        if (t > 0) {
            p0[i] = teach[b * (T_SZ * 2) + (t - 1) * 2 + 0];
            p1[i] = teach[b * (T_SZ * 2) + (t - 1) * 2 + 1];
        } else {
            p0[i] = 0.0f;
            p1[i] = 0.0f;
        }
    }

#pragma unroll
    for (int j = 0; j < 4; ++j) {
        int jj = j0 + tx * 4 + j;
        float wr0 = w_ih[jj * 2 + 0],            wr1 = w_ih[jj * 2 + 1];
        float wz0 = w_ih[(H_SZ + jj) * 2 + 0],   wz1 = w_ih[(H_SZ + jj) * 2 + 1];
        float wn0 = w_ih[(2 * H_SZ + jj) * 2 + 0], wn1 = w_ih[(2 * H_SZ + jj) * 2 + 1];
        float br = b_ih[jj], bz = b_ih[H_SZ + jj], bn = b_ih[2 * H_SZ + jj];
        float hbr = b_hh[jj], hbz = b_hh[H_SZ + jj], hbn = b_hh[2 * H_SZ + jj];
#pragma unroll
        for (int i = 0; i < 4; ++i) {
            int b = b0 + ty * 4 + i;
            float xr = wr0 * p0[i] + wr1 * p1[i] + br;
            float xz = wz0 * p0[i] + wz1 * p1[i] + bz;
            float xn = wn0 * p0[i] + wn1 * p1[i] + bn;
            float hr = acc[0][i][j] + hbr;
            float hz = acc[1][i][j] + hbz;
            float hn = acc[2][i][j] + hbn;
            float r = sigmoidf_(xr + hr);
            float z = sigmoidf_(xz + hz);
            float n = tanhf(xn + r * hn);
            float hold = h[b * H_SZ + jj];
            h_next[b * H_SZ + jj] = (1.0f - z) * n + z * hold;
        }
    }
}

// delta[b,:] = h_new[b,:] @ w_out^T + b_out  -> pred_deltas[b,t,:]
__global__ __launch_bounds__(256) void delta_kernel(
        const float* __restrict__ h, const float* __restrict__ w_out,
        const float* __restrict__ b_out, float* __restrict__ out, int t) {
    const int wave = (blockIdx.x * 256 + threadIdx.x) / 64;
    const int lane = threadIdx.x % 64;
    float s0 = 0.0f, s1 = 0.0f;
    for (int j = lane; j < H_SZ; j += 64) {
        float hv = h[wave * H_SZ + j];
        s0 += hv * w_out[j];
        s1 += hv * w_out[H_SZ + j];
    }
#pragma unroll
    for (int off = 32; off > 0; off >>= 1) {
        s0 += __shfl_down(s0, off, 64);
        s1 += __shfl_down(s1, off, 64);
    }
    if (lane == 0) {
        out[wave * (T_SZ * 2) + t * 2 + 0] = s0 + b_out[0];
        out[wave * (T_SZ * 2) + t * 2 + 1] = s1 + b_out[1];
    }
}

// pred_pos = cumsum(pred_deltas, axis=t)
__global__ __launch_bounds__(256) void cumsum_kernel(
        const float* __restrict__ deltas, float* __restrict__ pos) {
    int idx = blockIdx.x * 256 + threadIdx.x;  // b*2 + c
    if (idx >= B_SZ * 2) return;
    int b = idx >> 1, c = idx & 1;
    float acc = 0.0f;
    for (int t = 0; t < T_SZ; ++t) {
        acc += deltas[b * (T_SZ * 2) + t * 2 + c];
        pos[b * (T_SZ * 2) + t * 2 + c] = acc;
    }
}

extern "C" void kernel_launch(void* const* d_in, const int* in_sizes, int n_in,
                              void* d_out, int out_size, void* d_ws, size_t ws_size,
                              hipStream_t stream) {
    const float* ev     = (const float*)d_in[0];
    const float* teach  = (const float*)d_in[1];
    const float* w_init = (const float*)d_in[2];
    const float* b_init = (const float*)d_in[3];
    const float* w_ih   = (const float*)d_in[4];
    const float* w_hh   = (const float*)d_in[5];
    const float* b_ih   = (const float*)d_in[6];
    const float* b_hh   = (const float*)d_in[7];
    const float* w_out  = (const float*)d_in[8];
    const float* b_out  = (const float*)d_in[9];

    float* out = (float*)d_out;                    // pred_deltas (B,T,2)
    float* pos = out + (size_t)B_SZ * T_SZ * 2;    // pred_pos    (B,T,2)

    float* hA = (float*)d_ws;                      // ping-pong h buffers (16 MB each)
    float* hB = hA + (size_t)B_SZ * H_SZ;

    dim3 ggrid(H_SZ / BN, B_SZ / BM);
    h0_kernel<<<ggrid, 256, 0, stream>>>(ev, w_init, b_init, hA);

    float* hc = hA;
    float* hn = hB;
    for (int t = 0; t < T_SZ; ++t) {
        step_kernel<<<ggrid, 256, 0, stream>>>(hc, w_hh, b_hh, w_ih, b_ih, teach, hn, t);
        delta_kernel<<<B_SZ / 4, 256, 0, stream>>>(hn, w_out, b_out, out, t);
        float* tmp = hc; hc = hn; hn = tmp;
    }
    cumsum_kernel<<<(B_SZ * 2 + 255) / 256, 256, 0, stream>>>(out, pos);
}

// Round 2
// 5542.248 us; speedup vs baseline: 2.9618x; 2.9618x over previous
//
#include <hip/hip_runtime.h>
#include <hip/hip_bf16.h>
#include <math.h>

#define B_SZ 4096
#define D_SZ 1024
#define H_SZ 1024
#define T_SZ 50

typedef __attribute__((ext_vector_type(4))) float f32x4;
typedef __attribute__((ext_vector_type(4))) float f4;
typedef __attribute__((ext_vector_type(8))) short bf16x8;
typedef unsigned short ushort_t;

__device__ __forceinline__ float sigmoidf_(float x) {
    return 1.0f / (1.0f + expf(-x));
}

__device__ __forceinline__ float bf2f(ushort_t u) {
    unsigned v = ((unsigned)u) << 16;
    return __uint_as_float(v);
}

__device__ __forceinline__ ushort_t f2bf(float x) {
    __hip_bfloat16 h = __float2bfloat16(x);  // RNE
    ushort_t r;
    __builtin_memcpy(&r, &h, 2);
    return r;
}

__device__ __forceinline__ void split_bf16(float x, ushort_t* hi, ushort_t* lo) {
    ushort_t h = f2bf(x);
    float res = x - bf2f(h);
    *hi = h;
    *lo = f2bf(res);
}

// async global->LDS, 16 bytes per lane
__device__ __forceinline__ void gl_lds16(const ushort_t* g, ushort_t* l) {
    __builtin_amdgcn_global_load_lds(
        (const __attribute__((address_space(1))) unsigned int*)g,
        (__attribute__((address_space(3))) unsigned int*)l, 16, 0, 0);
}

// ---------------------------------------------------------------------------
// w_hh fp32 -> bf16 hi/lo split (once per call; 3M elements)
__global__ __launch_bounds__(256) void conv_w_kernel(
        const float* __restrict__ w, ushort_t* __restrict__ hi,
        ushort_t* __restrict__ lo) {
    int i = blockIdx.x * 256 + threadIdx.x;
    if (i < 3 * H_SZ * H_SZ) {
        ushort_t h, l;
        split_bf16(w[i], &h, &l);
        hi[i] = h;
        lo[i] = l;
    }
}

// ---------------------------------------------------------------------------
// h0 = tanh(ev @ w_init^T + b_init), fp32 VALU GEMM (runs once), writes hi/lo
#define BM0 64
#define BN0 64
#define BK0 16
__global__ __launch_bounds__(256) void h0_kernel(
        const float* __restrict__ ev, const float* __restrict__ w_init,
        const float* __restrict__ b_init, ushort_t* __restrict__ h_hi,
        ushort_t* __restrict__ h_lo) {
    __shared__ __align__(16) float sA[BK0][BM0];
    __shared__ __align__(16) float sW[BK0][BN0];
    const int tid = threadIdx.x;
    const int tx = tid % 16, ty = tid / 16;
    const int b0 = blockIdx.y * BM0, j0 = blockIdx.x * BN0;
    const int lrow = tid / 4, lc4 = tid % 4;

    float acc[4][4] = {};

    for (int k0 = 0; k0 < D_SZ; k0 += BK0) {
        f4 a4 = *(const f4*)&ev[(b0 + lrow) * D_SZ + k0 + lc4 * 4];
        f4 w4 = *(const f4*)&w_init[(j0 + lrow) * D_SZ + k0 + lc4 * 4];
        __syncthreads();
#pragma unroll
        for (int c = 0; c < 4; ++c) {
            sA[lc4 * 4 + c][lrow] = a4[c];
            sW[lc4 * 4 + c][lrow] = w4[c];
        }
        __syncthreads();
#pragma unroll
        for (int kk = 0; kk < BK0; ++kk) {
            f4 af = *(const f4*)&sA[kk][ty * 4];
            f4 wf = *(const f4*)&sW[kk][tx * 4];
#pragma unroll
            for (int i = 0; i < 4; ++i)
#pragma unroll
                for (int j = 0; j < 4; ++j)
                    acc[i][j] += af[i] * wf[j];
        }
    }

#pragma unroll
    for (int j = 0; j < 4; ++j) {
        int jj = j0 + tx * 4 + j;
        float bj = b_init[jj];
#pragma unroll
        for (int i = 0; i < 4; ++i) {
            int b = b0 + ty * 4 + i;
            ushort_t h, l;
            split_bf16(tanhf(acc[i][j] + bj), &h, &l);
            h_hi[b * H_SZ + jj] = h;
            h_lo[b * H_SZ + jj] = l;
        }
    }
}

// ---------------------------------------------------------------------------
// One GRU step via bf16x3 MFMA.
// Tile: 64 (batch) x [3 gates x 64 j].  256 threads = 4 waves, wave grid 2x2,
// wave tile 32(M) x 32(j) per gate.  BK=32, global_load_lds staging.
// LDS (shorts): A_hi[64][32]@0  A_lo@2048  B_hi[3][64][32]@4096  B_lo@10240
__global__ __launch_bounds__(256) void step_mfma_kernel(
        const ushort_t* __restrict__ h_hi, const ushort_t* __restrict__ h_lo,
        const ushort_t* __restrict__ w_hi, const ushort_t* __restrict__ w_lo,
        const float* __restrict__ b_hh, const float* __restrict__ w_ih,
        const float* __restrict__ b_ih, const float* __restrict__ teach,
        ushort_t* __restrict__ hn_hi, ushort_t* __restrict__ hn_lo, int t) {
    __shared__ __align__(16) ushort_t lds[16384];  // 32 KB

    const int tid = threadIdx.x;
    const int b0 = blockIdx.y * 64;
    const int j0 = blockIdx.x * 64;

    // staging role: row 0..63, 16-byte chunk 0..3 within the 64-elem k-row
    const int srow = tid >> 2, sch = tid & 3;

    // compute role
    const int lane = tid & 63, wave = tid >> 6;
    const int wm = wave >> 1, wn = wave & 1;
    const int lrow = lane & 15, quad = lane >> 4;

    const ushort_t* gA_hi = h_hi + (size_t)(b0 + srow) * H_SZ + sch * 8;
    const ushort_t* gA_lo = h_lo + (size_t)(b0 + srow) * H_SZ + sch * 8;
    const ushort_t* gB_hi0 = w_hi + (size_t)(0 * H_SZ + j0 + srow) * H_SZ + sch * 8;
    const ushort_t* gB_hi1 = w_hi + (size_t)(1 * H_SZ + j0 + srow) * H_SZ + sch * 8;
    const ushort_t* gB_hi2 = w_hi + (size_t)(2 * H_SZ + j0 + srow) * H_SZ + sch * 8;
    const ushort_t* gB_lo0 = w_lo + (size_t)(0 * H_SZ + j0 + srow) * H_SZ + sch * 8;
    const ushort_t* gB_lo1 = w_lo + (size_t)(1 * H_SZ + j0 + srow) * H_SZ + sch * 8;
    const ushort_t* gB_lo2 = w_lo + (size_t)(2 * H_SZ + j0 + srow) * H_SZ + sch * 8;
    ushort_t* stA_hi = &lds[0] + tid * 8;
    ushort_t* stA_lo = &lds[2048] + tid * 8;
    ushort_t* stB_hi = &lds[4096] + tid * 8;   // +g*2048
    ushort_t* stB_lo = &lds[10240] + tid * 8;  // +g*2048

    f32x4 acc[3][2][2];
#pragma unroll
    for (int g = 0; g < 3; ++g)
#pragma unroll
        for (int mi = 0; mi < 2; ++mi)
#pragma unroll
            for (int ni = 0; ni < 2; ++ni)
                acc[g][mi][ni] = (f32x4){0.f, 0.f, 0.f, 0.f};

    // LDS read offsets (in shorts)
    int roffA0 = (wm * 32 + 0 * 16 + lrow) * 32 + quad * 8;
    int roffA1 = (wm * 32 + 1 * 16 + lrow) * 32 + quad * 8;
    int roffB0 = (wn * 32 + 0 * 16 + lrow) * 32 + quad * 8;
    int roffB1 = (wn * 32 + 1 * 16 + lrow) * 32 + quad * 8;

    for (int k0 = 0; k0 < H_SZ; k0 += 32) {
        __syncthreads();  // prev iteration's readers done
        gl_lds16(gA_hi + k0, stA_hi);
        gl_lds16(gA_lo + k0, stA_lo);
        gl_lds16(gB_hi0 + k0, stB_hi + 0 * 2048);
        gl_lds16(gB_hi1 + k0, stB_hi + 1 * 2048);
        gl_lds16(gB_hi2 + k0, stB_hi + 2 * 2048);
        gl_lds16(gB_lo0 + k0, stB_lo + 0 * 2048);
        gl_lds16(gB_lo1 + k0, stB_lo + 1 * 2048);
        gl_lds16(gB_lo2 + k0, stB_lo + 2 * 2048);
        __syncthreads();  // loads landed (vmcnt drained before barrier)

        bf16x8 aH[2], aL[2];
        aH[0] = *(const bf16x8*)&lds[0 + roffA0];
        aH[1] = *(const bf16x8*)&lds[0 + roffA1];
        aL[0] = *(const bf16x8*)&lds[2048 + roffA0];
        aL[1] = *(const bf16x8*)&lds[2048 + roffA1];
#pragma unroll
        for (int g = 0; g < 3; ++g) {
            bf16x8 bH0 = *(const bf16x8*)&lds[4096 + g * 2048 + roffB0];
            bf16x8 bH1 = *(const bf16x8*)&lds[4096 + g * 2048 + roffB1];
            bf16x8 bL0 = *(const bf16x8*)&lds[10240 + g * 2048 + roffB0];
            bf16x8 bL1 = *(const bf16x8*)&lds[10240 + g * 2048 + roffB1];
#pragma unroll
            for (int mi = 0; mi < 2; ++mi) {
                acc[g][mi][0] = __builtin_amdgcn_mfma_f32_16x16x32_bf16(
                    aH[mi], bH0, acc[g][mi][0], 0, 0, 0);
                acc[g][mi][0] = __builtin_amdgcn_mfma_f32_16x16x32_bf16(
                    aH[mi], bL0, acc[g][mi][0], 0, 0, 0);
                acc[g][mi][0] = __builtin_amdgcn_mfma_f32_16x16x32_bf16(
                    aL[mi], bH0, acc[g][mi][0], 0, 0, 0);
                acc[g][mi][1] = __builtin_amdgcn_mfma_f32_16x16x32_bf16(
                    aH[mi], bH1, acc[g][mi][1], 0, 0, 0);
                acc[g][mi][1] = __builtin_amdgcn_mfma_f32_16x16x32_bf16(
                    aH[mi], bL1, acc[g][mi][1], 0, 0, 0);
                acc[g][mi][1] = __builtin_amdgcn_mfma_f32_16x16x32_bf16(
                    aL[mi], bH1, acc[g][mi][1], 0, 0, 0);
            }
        }
    }

    // ---------------- fused GRU epilogue ----------------
    // D layout per 16x16 frag: row(M) = quad*4 + reg, col(N=j) = lrow
#pragma unroll
    for (int ni = 0; ni < 2; ++ni) {
        const int j = j0 + wn * 32 + ni * 16 + lrow;
        const float wr0 = w_ih[(0 * H_SZ + j) * 2 + 0];
        const float wr1 = w_ih[(0 * H_SZ + j) * 2 + 1];
        const float wz0 = w_ih[(1 * H_SZ + j) * 2 + 0];
        const float wz1 = w_ih[(1 * H_SZ + j) * 2 + 1];
        const float wn0 = w_ih[(2 * H_SZ + j) * 2 + 0];
        const float wn1 = w_ih[(2 * H_SZ + j) * 2 + 1];
        const float br = b_ih[0 * H_SZ + j] + b_hh[0 * H_SZ + j];
        const float bz = b_ih[1 * H_SZ + j] + b_hh[1 * H_SZ + j];
        const float bn = b_ih[2 * H_SZ + j];
        const float hbn = b_hh[2 * H_SZ + j];
#pragma unroll
        for (int mi = 0; mi < 2; ++mi) {
#pragma unroll
            for (int reg = 0; reg < 4; ++reg) {
                const int b = b0 + wm * 32 + mi * 16 + quad * 4 + reg;
                float p0 = 0.f, p1 = 0.f;
                if (t > 0) {
                    p0 = teach[b * (T_SZ * 2) + (t - 1) * 2 + 0];
                    p1 = teach[b * (T_SZ * 2) + (t - 1) * 2 + 1];
                }
                const float hr = acc[0][mi][ni][reg];
                const float hz = acc[1][mi][ni][reg];
                const float hn_ = acc[2][mi][ni][reg] + hbn;
                const float xr = wr0 * p0 + wr1 * p1 + br;
                const float xz = wz0 * p0 + wz1 * p1 + bz;
                const float xn = wn0 * p0 + wn1 * p1 + bn;
                const float r = sigmoidf_(xr + hr);
                const float z = sigmoidf_(xz + hz);
                const float n = tanhf(xn + r * hn_);
                const size_t idx = (size_t)b * H_SZ + j;
                const float hold = bf2f(h_hi[idx]) + bf2f(h_lo[idx]);
                ushort_t oh, ol;
                split_bf16((1.0f - z) * n + z * hold, &oh, &ol);
                hn_hi[idx] = oh;
                hn_lo[idx] = ol;
            }
        }
    }
}

// ---------------------------------------------------------------------------
// delta[b,:] = h[b,:] @ w_out^T + b_out   (h reconstructed from hi/lo)
__global__ __launch_bounds__(256) void delta_kernel(
        const ushort_t* __restrict__ h_hi, const ushort_t* __restrict__ h_lo,
        const float* __restrict__ w_out, const float* __restrict__ b_out,
        float* __restrict__ out, int t) {
    const int row = (blockIdx.x * 256 + threadIdx.x) / 64;
    const int lane = threadIdx.x % 64;
    float s0 = 0.0f, s1 = 0.0f;
    for (int j = lane; j < H_SZ; j += 64) {
        size_t idx = (size_t)row * H_SZ + j;
        float hv = bf2f(h_hi[idx]) + bf2f(h_lo[idx]);
        s0 += hv * w_out[j];
        s1 += hv * w_out[H_SZ + j];
    }
#pragma unroll
    for (int off = 32; off > 0; off >>= 1) {
        s0 += __shfl_down(s0, off, 64);
        s1 += __shfl_down(s1, off, 64);
    }
    if (lane == 0) {
        out[row * (T_SZ * 2) + t * 2 + 0] = s0 + b_out[0];
        out[row * (T_SZ * 2) + t * 2 + 1] = s1 + b_out[1];
    }
}

// ---------------------------------------------------------------------------
__global__ __launch_bounds__(256) void cumsum_kernel(
        const float* __restrict__ deltas, float* __restrict__ pos) {
    int idx = blockIdx.x * 256 + threadIdx.x;
    if (idx >= B_SZ * 2) return;
    int b = idx >> 1, c = idx & 1;
    float acc = 0.0f;
    for (int t = 0; t < T_SZ; ++t) {
        acc += deltas[b * (T_SZ * 2) + t * 2 + c];
        pos[b * (T_SZ * 2) + t * 2 + c] = acc;
    }
}

// ---------------------------------------------------------------------------
extern "C" void kernel_launch(void* const* d_in, const int* in_sizes, int n_in,
                              void* d_out, int out_size, void* d_ws, size_t ws_size,
                              hipStream_t stream) {
    const float* ev     = (const float*)d_in[0];
    const float* teach  = (const float*)d_in[1];
    const float* w_init = (const float*)d_in[2];
    const float* b_init = (const float*)d_in[3];
    const float* w_ih   = (const float*)d_in[4];
    const float* w_hh   = (const float*)d_in[5];
    const float* b_ih   = (const float*)d_in[6];
    const float* b_hh   = (const float*)d_in[7];
    const float* w_out  = (const float*)d_in[8];
    const float* b_out  = (const float*)d_in[9];

    float* out = (float*)d_out;                  // pred_deltas (B,T,2)
    float* pos = out + (size_t)B_SZ * T_SZ * 2;  // pred_pos    (B,T,2)

    // workspace layout (shorts): 4 x h (4M each) + w hi/lo (3M each) = 44 MB
    ushort_t* ws = (ushort_t*)d_ws;
    ushort_t* hA_hi = ws;
    ushort_t* hA_lo = hA_hi + (size_t)B_SZ * H_SZ;
    ushort_t* hB_hi = hA_lo + (size_t)B_SZ * H_SZ;
    ushort_t* hB_lo = hB_hi + (size_t)B_SZ * H_SZ;
    ushort_t* whh_hi = hB_lo + (size_t)B_SZ * H_SZ;
    ushort_t* whh_lo = whh_hi + (size_t)3 * H_SZ * H_SZ;

    conv_w_kernel<<<(3 * H_SZ * H_SZ) / 256, 256, 0, stream>>>(w_hh, whh_hi, whh_lo);

    dim3 g0(H_SZ / BN0, B_SZ / BM0);
    h0_kernel<<<g0, 256, 0, stream>>>(ev, w_init, b_init, hA_hi, hA_lo);

    dim3 gs(H_SZ / 64, B_SZ / 64);  // (16, 64) = 1024 blocks
    ushort_t *hc_hi = hA_hi, *hc_lo = hA_lo, *hn_hi = hB_hi, *hn_lo = hB_lo;
    for (int t = 0; t < T_SZ; ++t) {
        step_mfma_kernel<<<gs, 256, 0, stream>>>(hc_hi, hc_lo, whh_hi, whh_lo,
                                                 b_hh, w_ih, b_ih, teach,
                                                 hn_hi, hn_lo, t);
        delta_kernel<<<B_SZ / 4, 256, 0, stream>>>(hn_hi, hn_lo, w_out, b_out, out, t);
        ushort_t* tmp;
        tmp = hc_hi; hc_hi = hn_hi; hn_hi = tmp;
        tmp = hc_lo; hc_lo = hn_lo; hn_lo = tmp;
    }
    cumsum_kernel<<<(B_SZ * 2 + 255) / 256, 256, 0, stream>>>(out, pos);
}

// Round 3
// 3538.199 us; speedup vs baseline: 4.6394x; 1.5664x over previous
//
#include <hip/hip_runtime.h>
#include <math.h>

#define B_SZ 4096
#define D_SZ 1024
#define H_SZ 1024
#define T_SZ 50

typedef _Float16 f16;
typedef __attribute__((ext_vector_type(8))) _Float16 f16x8;
typedef __attribute__((ext_vector_type(4))) _Float16 f16x4;
typedef __attribute__((ext_vector_type(4))) float f32x4;
typedef __attribute__((ext_vector_type(4))) float f4;

__device__ __forceinline__ float sigmoidf_(float x) {
    return 1.0f / (1.0f + expf(-x));
}

// async global->LDS, 16 bytes per lane
__device__ __forceinline__ void gl_lds16(const void* g, void* l) {
    __builtin_amdgcn_global_load_lds(
        (const __attribute__((address_space(1))) unsigned int*)g,
        (__attribute__((address_space(3))) unsigned int*)l, 16, 0, 0);
}

// ---------------------------------------------------------------------------
// fp32 -> fp16 conversion (4 elems/thread; n divisible by 4)
__global__ __launch_bounds__(256) void conv_kernel(
        const float* __restrict__ s, f16* __restrict__ d, int n) {
    int i = (blockIdx.x * 256 + threadIdx.x) * 4;
    if (i < n) {
        f4 v = *(const f4*)&s[i];
        f16x4 o = {(f16)v[0], (f16)v[1], (f16)v[2], (f16)v[3]};
        *(f16x4*)&d[i] = o;
    }
}

// ---------------------------------------------------------------------------
// h0 = tanh(ev @ w_init^T + b_init) via fp16 MFMA (single pass).
// Tile 128(M) x 64(N), 4 waves 2x2, wave 64x32 (4 mi x 2 ni frags 16x16x32).
__global__ __launch_bounds__(256, 2) void h0_kernel(
        const f16* __restrict__ ev, const f16* __restrict__ wi,
        const float* __restrict__ b_init, f16* __restrict__ hh,
        f16* __restrict__ hl) {
    __shared__ __align__(16) f16 lds[6144];  // A 128x32 @0, B 64x32 @4096
    const int tid = threadIdx.x;
    const int lane = tid & 63, wave = tid >> 6;
    const int b0 = blockIdx.y * 128, j0 = blockIdx.x * 64;
    const int wm = wave >> 1, wn = wave & 1;
    const int lrow = lane & 15, quad = lane >> 4;

    // staging descriptors: 12 wave-chunks (A=8, B=4), 3 issues/thread
    const f16* gsrc[3];
    int lbase[3];
    {
        const int row16 = lane >> 2, part = lane & 3;
#pragma unroll
        for (int i = 0; i < 3; ++i) {
            int c = wave + 4 * i;
            if (c < 8) {
                gsrc[i] = ev + (size_t)(b0 + c * 16 + row16) * D_SZ + part * 8;
                lbase[i] = c * 512;
            } else {
                int cc = c - 8;
                gsrc[i] = wi + (size_t)(j0 + cc * 16 + row16) * D_SZ + part * 8;
                lbase[i] = 4096 + cc * 512;
            }
        }
    }

    int offA[4], offB[2];
#pragma unroll
    for (int mi = 0; mi < 4; ++mi)
        offA[mi] = (wm * 64 + mi * 16 + lrow) * 32 + quad * 8;
#pragma unroll
    for (int ni = 0; ni < 2; ++ni)
        offB[ni] = 4096 + (wn * 32 + ni * 16 + lrow) * 32 + quad * 8;

    f32x4 acc[4][2] = {};

    for (int k0 = 0; k0 < D_SZ; k0 += 32) {
        __syncthreads();
#pragma unroll
        for (int i = 0; i < 3; ++i)
            gl_lds16(gsrc[i] + k0, &lds[lbase[i]] + lane * 8);
        __syncthreads();
        f16x8 aa[4], bb[2];
#pragma unroll
        for (int mi = 0; mi < 4; ++mi) aa[mi] = *(const f16x8*)&lds[offA[mi]];
#pragma unroll
        for (int ni = 0; ni < 2; ++ni) bb[ni] = *(const f16x8*)&lds[offB[ni]];
#pragma unroll
        for (int mi = 0; mi < 4; ++mi)
#pragma unroll
            for (int ni = 0; ni < 2; ++ni)
                acc[mi][ni] = __builtin_amdgcn_mfma_f32_16x16x32_f16(
                    aa[mi], bb[ni], acc[mi][ni], 0, 0, 0);
    }

#pragma unroll
    for (int ni = 0; ni < 2; ++ni) {
        const int j = j0 + wn * 32 + ni * 16 + lrow;
        const float bj = b_init[j];
#pragma unroll
        for (int mi = 0; mi < 4; ++mi)
#pragma unroll
            for (int reg = 0; reg < 4; ++reg) {
                const int b = b0 + wm * 64 + mi * 16 + quad * 4 + reg;
                float v = tanhf(acc[mi][ni][reg] + bj);
                f16 oh = (f16)v;
                f16 ol = (f16)(v - (float)oh);
                size_t idx = (size_t)b * H_SZ + j;
                hh[idx] = oh;
                hl[idx] = ol;
            }
    }
}

// ---------------------------------------------------------------------------
// One GRU step: gh = h @ w_hh^T via fp16 2-pass MFMA (h = hi+lo, w single).
// Tile 128(M) x 64(j) x 3 gates. 4 waves 2x2, wave 64x32 per gate.
// LDS (f16): A_hi[128][32]@0, A_lo@4096, B[3][64][32]@8192  -> 28 KB.
// Epilogue: fused GRU gates + h_next hi/lo store + delta partial atomics.
__global__ __launch_bounds__(256, 2) void step_kernel(
        const f16* __restrict__ hh, const f16* __restrict__ hl,
        const f16* __restrict__ w, const float* __restrict__ b_hh,
        const float* __restrict__ w_ih, const float* __restrict__ b_ih,
        const float* __restrict__ w_out, const float* __restrict__ teach,
        f16* __restrict__ nhh, f16* __restrict__ nhl,
        float* __restrict__ out, int t) {
    __shared__ __align__(16) f16 lds[14336];
    const int tid = threadIdx.x;
    const int lane = tid & 63, wave = tid >> 6;
    const int b0 = blockIdx.y * 128, j0 = blockIdx.x * 64;
    const int wm = wave >> 1, wn = wave & 1;
    const int lrow = lane & 15, quad = lane >> 4;

    // staging: 28 wave-chunks (A_hi 8, A_lo 8, B 12), 7 issues/thread
    const f16* gsrc[7];
    int lbase[7];
    {
        const int row16 = lane >> 2, part = lane & 3;
#pragma unroll
        for (int i = 0; i < 7; ++i) {
            int c = wave + 4 * i;
            if (c < 8) {
                gsrc[i] = hh + (size_t)(b0 + c * 16 + row16) * H_SZ + part * 8;
                lbase[i] = c * 512;
            } else if (c < 16) {
                int cc = c - 8;
                gsrc[i] = hl + (size_t)(b0 + cc * 16 + row16) * H_SZ + part * 8;
                lbase[i] = 4096 + cc * 512;
            } else {
                int cc = c - 16, g = cc >> 2, sub = cc & 3;
                gsrc[i] = w + (size_t)(g * H_SZ + j0 + sub * 16 + row16) * H_SZ + part * 8;
                lbase[i] = 8192 + g * 2048 + sub * 512;
            }
        }
    }

    int offA[4], offB[3][2];
#pragma unroll
    for (int mi = 0; mi < 4; ++mi)
        offA[mi] = (wm * 64 + mi * 16 + lrow) * 32 + quad * 8;
#pragma unroll
    for (int g = 0; g < 3; ++g)
#pragma unroll
        for (int ni = 0; ni < 2; ++ni)
            offB[g][ni] = 8192 + g * 2048 + (wn * 32 + ni * 16 + lrow) * 32 + quad * 8;

    f32x4 acc[3][4][2] = {};

    for (int k0 = 0; k0 < H_SZ; k0 += 32) {
        __syncthreads();
#pragma unroll
        for (int i = 0; i < 7; ++i)
            gl_lds16(gsrc[i] + k0, &lds[lbase[i]] + lane * 8);
        __syncthreads();
        f16x8 aH[4], aL[4], bb[3][2];
#pragma unroll
        for (int mi = 0; mi < 4; ++mi) {
            aH[mi] = *(const f16x8*)&lds[offA[mi]];
            aL[mi] = *(const f16x8*)&lds[4096 + offA[mi]];
        }
#pragma unroll
        for (int g = 0; g < 3; ++g)
#pragma unroll
            for (int ni = 0; ni < 2; ++ni)
                bb[g][ni] = *(const f16x8*)&lds[offB[g][ni]];
#pragma unroll
        for (int g = 0; g < 3; ++g)
#pragma unroll
            for (int mi = 0; mi < 4; ++mi)
#pragma unroll
                for (int ni = 0; ni < 2; ++ni) {
                    acc[g][mi][ni] = __builtin_amdgcn_mfma_f32_16x16x32_f16(
                        aH[mi], bb[g][ni], acc[g][mi][ni], 0, 0, 0);
                    acc[g][mi][ni] = __builtin_amdgcn_mfma_f32_16x16x32_f16(
                        aL[mi], bb[g][ni], acc[g][mi][ni], 0, 0, 0);
                }
    }

    // -------- fused epilogue: gates, h_next, delta partials --------
#pragma unroll
    for (int mi = 0; mi < 4; ++mi) {
        float p0[4], p1[4];
#pragma unroll
        for (int reg = 0; reg < 4; ++reg) {
            const int b = b0 + wm * 64 + mi * 16 + quad * 4 + reg;
            if (t > 0) {
                p0[reg] = teach[b * (T_SZ * 2) + (t - 1) * 2 + 0];
                p1[reg] = teach[b * (T_SZ * 2) + (t - 1) * 2 + 1];
            } else {
                p0[reg] = 0.f;
                p1[reg] = 0.f;
            }
        }
        float s0[4] = {0.f, 0.f, 0.f, 0.f};
        float s1[4] = {0.f, 0.f, 0.f, 0.f};
#pragma unroll
        for (int ni = 0; ni < 2; ++ni) {
            const int j = j0 + wn * 32 + ni * 16 + lrow;
            const float wr0 = w_ih[(0 * H_SZ + j) * 2 + 0];
            const float wr1 = w_ih[(0 * H_SZ + j) * 2 + 1];
            const float wz0 = w_ih[(1 * H_SZ + j) * 2 + 0];
            const float wz1 = w_ih[(1 * H_SZ + j) * 2 + 1];
            const float wn0 = w_ih[(2 * H_SZ + j) * 2 + 0];
            const float wn1 = w_ih[(2 * H_SZ + j) * 2 + 1];
            const float br = b_ih[0 * H_SZ + j] + b_hh[0 * H_SZ + j];
            const float bz = b_ih[1 * H_SZ + j] + b_hh[1 * H_SZ + j];
            const float bn = b_ih[2 * H_SZ + j];
            const float hbn = b_hh[2 * H_SZ + j];
            const float wo0 = w_out[j], wo1 = w_out[H_SZ + j];
#pragma unroll
            for (int reg = 0; reg < 4; ++reg) {
                const int b = b0 + wm * 64 + mi * 16 + quad * 4 + reg;
                const float hr = acc[0][mi][ni][reg];
                const float hz = acc[1][mi][ni][reg];
                const float hn_ = acc[2][mi][ni][reg] + hbn;
                const float xr = wr0 * p0[reg] + wr1 * p1[reg] + br;
                const float xz = wz0 * p0[reg] + wz1 * p1[reg] + bz;
                const float xn = wn0 * p0[reg] + wn1 * p1[reg] + bn;
                const float r = sigmoidf_(xr + hr);
                const float z = sigmoidf_(xz + hz);
                const float n = tanhf(xn + r * hn_);
                const size_t idx = (size_t)b * H_SZ + j;
                const float hold = (float)hh[idx] + (float)hl[idx];
                const float hnew = (1.0f - z) * n + z * hold;
                f16 oh = (f16)hnew;
                f16 ol = (f16)(hnew - (float)oh);
                nhh[idx] = oh;
                nhl[idx] = ol;
                s0[reg] += hnew * wo0;
                s1[reg] += hnew * wo1;
            }
        }
#pragma unroll
        for (int reg = 0; reg < 4; ++reg) {
#pragma unroll
            for (int m = 1; m < 16; m <<= 1) {
                s0[reg] += __shfl_xor(s0[reg], m);
                s1[reg] += __shfl_xor(s1[reg], m);
            }
            if (lrow == 0) {
                const int b = b0 + wm * 64 + mi * 16 + quad * 4 + reg;
                atomicAdd(&out[b * (T_SZ * 2) + t * 2 + 0], s0[reg]);
                atomicAdd(&out[b * (T_SZ * 2) + t * 2 + 1], s1[reg]);
            }
        }
    }
}

// ---------------------------------------------------------------------------
// pred_deltas += b_out; pred_pos = cumsum
__global__ __launch_bounds__(256) void final_kernel(
        float* __restrict__ out, float* __restrict__ pos,
        const float* __restrict__ b_out) {
    int idx = blockIdx.x * 256 + threadIdx.x;  // b*2 + c
    if (idx >= B_SZ * 2) return;
    int b = idx >> 1, c = idx & 1;
    float bc = b_out[c];
    float acc = 0.0f;
    for (int t = 0; t < T_SZ; ++t) {
        float d = out[b * (T_SZ * 2) + t * 2 + c] + bc;
        out[b * (T_SZ * 2) + t * 2 + c] = d;
        acc += d;
        pos[b * (T_SZ * 2) + t * 2 + c] = acc;
    }
}

// ---------------------------------------------------------------------------
extern "C" void kernel_launch(void* const* d_in, const int* in_sizes, int n_in,
                              void* d_out, int out_size, void* d_ws, size_t ws_size,
                              hipStream_t stream) {
    const float* ev     = (const float*)d_in[0];
    const float* teach  = (const float*)d_in[1];
    const float* w_init = (const float*)d_in[2];
    const float* b_init = (const float*)d_in[3];
    const float* w_ih   = (const float*)d_in[4];
    const float* w_hh   = (const float*)d_in[5];
    const float* b_ih   = (const float*)d_in[6];
    const float* b_hh   = (const float*)d_in[7];
    const float* w_out  = (const float*)d_in[8];
    const float* b_out  = (const float*)d_in[9];

    float* out = (float*)d_out;                  // pred_deltas (B,T,2)
    float* pos = out + (size_t)B_SZ * T_SZ * 2;  // pred_pos    (B,T,2)

    // ws layout (f16 units): hA hi/lo, hB hi/lo (4M each), w_hh (3M), w_init (1M)
    // ev_f16 (4M) aliases hB_hi (consumed by h0 before hB is first written).
    f16* ws = (f16*)d_ws;
    f16* hA_hi = ws;
    f16* hA_lo = hA_hi + (size_t)B_SZ * H_SZ;
    f16* hB_hi = hA_lo + (size_t)B_SZ * H_SZ;
    f16* hB_lo = hB_hi + (size_t)B_SZ * H_SZ;
    f16* whh   = hB_lo + (size_t)B_SZ * H_SZ;
    f16* winit = whh + (size_t)3 * H_SZ * H_SZ;
    f16* evf   = hB_hi;  // alias

    hipMemsetAsync(out, 0, (size_t)B_SZ * T_SZ * 2 * sizeof(float), stream);

    conv_kernel<<<(3 * H_SZ * H_SZ) / 1024, 256, 0, stream>>>(w_hh, whh, 3 * H_SZ * H_SZ);
    conv_kernel<<<(H_SZ * D_SZ) / 1024, 256, 0, stream>>>(w_init, winit, H_SZ * D_SZ);
    conv_kernel<<<(B_SZ * D_SZ) / 1024, 256, 0, stream>>>(ev, evf, B_SZ * D_SZ);

    dim3 grid(H_SZ / 64, B_SZ / 128);  // (16, 32) = 512 blocks
    h0_kernel<<<grid, 256, 0, stream>>>(evf, winit, b_init, hA_hi, hA_lo);

    f16 *hc_hi = hA_hi, *hc_lo = hA_lo, *hn_hi = hB_hi, *hn_lo = hB_lo;
    for (int t = 0; t < T_SZ; ++t) {
        step_kernel<<<grid, 256, 0, stream>>>(hc_hi, hc_lo, whh, b_hh, w_ih,
                                              b_ih, w_out, teach, hn_hi, hn_lo,
                                              out, t);
        f16* tmp;
        tmp = hc_hi; hc_hi = hn_hi; hn_hi = tmp;
        tmp = hc_lo; hc_lo = hn_lo; hn_lo = tmp;
    }
    final_kernel<<<(B_SZ * 2 + 255) / 256, 256, 0, stream>>>(out, pos, b_out);
}

// Round 4
// 2613.739 us; speedup vs baseline: 6.2804x; 1.3537x over previous
//
#include <hip/hip_runtime.h>
#include <math.h>

#define B_SZ 4096
#define D_SZ 1024
#define H_SZ 1024
#define T_SZ 50

typedef _Float16 f16;
typedef __attribute__((ext_vector_type(8))) _Float16 f16x8;
typedef __attribute__((ext_vector_type(4))) _Float16 f16x4;
typedef __attribute__((ext_vector_type(4))) float f32x4;
typedef __attribute__((ext_vector_type(4))) float f4;

__device__ __forceinline__ float sigmoidf_(float x) {
    return 1.0f / (1.0f + expf(-x));
}

// async global->LDS, 16 bytes per lane
__device__ __forceinline__ void gl_lds16(const void* g, void* l) {
    __builtin_amdgcn_global_load_lds(
        (const __attribute__((address_space(1))) unsigned int*)g,
        (__attribute__((address_space(3))) unsigned int*)l, 16, 0, 0);
}

// ---------------------------------------------------------------------------
// fp32 -> fp16 conversion (4 elems/thread; n divisible by 4)
__global__ __launch_bounds__(256) void conv_kernel(
        const float* __restrict__ s, f16* __restrict__ d, int n) {
    int i = (blockIdx.x * 256 + threadIdx.x) * 4;
    if (i < n) {
        f4 v = *(const f4*)&s[i];
        f16x4 o = {(f16)v[0], (f16)v[1], (f16)v[2], (f16)v[3]};
        *(f16x4*)&d[i] = o;
    }
}

// ---------------------------------------------------------------------------
// h0 = tanh(ev @ w_init^T + b_init) via fp16 MFMA (single pass, single store).
// Tile 128(M) x 64(N), 4 waves 2x2, wave 64x32 (4 mi x 2 ni frags 16x16x32).
__global__ __launch_bounds__(256, 2) void h0_kernel(
        const f16* __restrict__ ev, const f16* __restrict__ wi,
        const float* __restrict__ b_init, f16* __restrict__ hh) {
    __shared__ __align__(16) f16 lds[6144];  // A 128x32 @0, B 64x32 @4096
    const int tid = threadIdx.x;
    const int lane = tid & 63, wave = tid >> 6;
    const int b0 = blockIdx.y * 128, j0 = blockIdx.x * 64;
    const int wm = wave >> 1, wn = wave & 1;
    const int lrow = lane & 15, quad = lane >> 4;

    // staging: 12 wave-chunks (A=8, B=4), 3 issues/thread
    const f16* gsrc[3];
    int lbase[3];
    {
        const int row16 = lane >> 2, part = lane & 3;
#pragma unroll
        for (int i = 0; i < 3; ++i) {
            int c = wave + 4 * i;
            if (c < 8) {
                gsrc[i] = ev + (size_t)(b0 + c * 16 + row16) * D_SZ + part * 8;
                lbase[i] = c * 512;
            } else {
                int cc = c - 8;
                gsrc[i] = wi + (size_t)(j0 + cc * 16 + row16) * D_SZ + part * 8;
                lbase[i] = 4096 + cc * 512;
            }
        }
    }

    int offA[4], offB[2];
#pragma unroll
    for (int mi = 0; mi < 4; ++mi)
        offA[mi] = (wm * 64 + mi * 16 + lrow) * 32 + quad * 8;
#pragma unroll
    for (int ni = 0; ni < 2; ++ni)
        offB[ni] = 4096 + (wn * 32 + ni * 16 + lrow) * 32 + quad * 8;

    f32x4 acc[4][2] = {};

    for (int k0 = 0; k0 < D_SZ; k0 += 32) {
        __syncthreads();
#pragma unroll
        for (int i = 0; i < 3; ++i)
            gl_lds16(gsrc[i] + k0, &lds[lbase[i]] + lane * 8);
        __syncthreads();
        f16x8 aa[4], bb[2];
#pragma unroll
        for (int mi = 0; mi < 4; ++mi) aa[mi] = *(const f16x8*)&lds[offA[mi]];
#pragma unroll
        for (int ni = 0; ni < 2; ++ni) bb[ni] = *(const f16x8*)&lds[offB[ni]];
#pragma unroll
        for (int mi = 0; mi < 4; ++mi)
#pragma unroll
            for (int ni = 0; ni < 2; ++ni)
                acc[mi][ni] = __builtin_amdgcn_mfma_f32_16x16x32_f16(
                    aa[mi], bb[ni], acc[mi][ni], 0, 0, 0);
    }

#pragma unroll
    for (int ni = 0; ni < 2; ++ni) {
        const int j = j0 + wn * 32 + ni * 16 + lrow;
        const float bj = b_init[j];
#pragma unroll
        for (int mi = 0; mi < 4; ++mi)
#pragma unroll
            for (int reg = 0; reg < 4; ++reg) {
                const int b = b0 + wm * 64 + mi * 16 + quad * 4 + reg;
                hh[(size_t)b * H_SZ + j] = (f16)tanhf(acc[mi][ni][reg] + bj);
            }
    }
}

// ---------------------------------------------------------------------------
// One GRU step: gh = h @ w_hh^T, single-pass fp16 MFMA.
// Tile 128(M) x 64(j) x 3 gates. 4 waves 2x2, wave 64x32 per gate.
// BK=64 as two concatenated BK=32 tiles (one barrier-pair per 64 k).
// LDS (f16): A[2][128][32] @0 (8192), B[2][3][64][32] @8192 (12288) = 40 KB.
__global__ __launch_bounds__(256, 2) void step_kernel(
        const f16* __restrict__ hh, const f16* __restrict__ w,
        const float* __restrict__ b_hh, const float* __restrict__ w_ih,
        const float* __restrict__ b_ih, const float* __restrict__ w_out,
        const float* __restrict__ teach, f16* __restrict__ nhh,
        float* __restrict__ out, int t) {
    __shared__ __align__(16) f16 lds[20480];
    const int tid = threadIdx.x;
    const int lane = tid & 63, wave = tid >> 6;
    const int b0 = blockIdx.y * 128, j0 = blockIdx.x * 64;
    const int wm = wave >> 1, wn = wave & 1;
    const int lrow = lane & 15, quad = lane >> 4;

    // staging: 40 wave-issues (A 16: 2 halves x 8; B 24: 2 halves x 12),
    // 10 issues/thread.  Each issue: 16 rows x 4 chunks of 16B.
    const f16* gsrc[10];
    int lbase[10];
    {
        const int r4 = lane >> 2, c4 = lane & 3;
#pragma unroll
        for (int i = 0; i < 10; ++i) {
            int m = wave + 4 * i;
            if (m < 16) {
                int half = m >> 3, sub = m & 7;
                gsrc[i] = hh + (size_t)(b0 + sub * 16 + r4) * H_SZ + half * 32 + c4 * 8;
                lbase[i] = half * 4096 + sub * 512 + lane * 8;
            } else {
                int mb = m - 16;
                int half = (mb >= 12) ? 1 : 0;
                int sub = mb - half * 12;
                int gr = sub * 16 + r4;  // 0..191 = gate*64 + jj
                gsrc[i] = w + (size_t)((gr >> 6) * H_SZ + j0 + (gr & 63)) * H_SZ +
                          half * 32 + c4 * 8;
                lbase[i] = 8192 + half * 6144 + sub * 512 + lane * 8;
            }
        }
    }

    int offA[4], offB[3][2];
#pragma unroll
    for (int mi = 0; mi < 4; ++mi)
        offA[mi] = (wm * 64 + mi * 16 + lrow) * 32 + quad * 8;
#pragma unroll
    for (int g = 0; g < 3; ++g)
#pragma unroll
        for (int ni = 0; ni < 2; ++ni)
            offB[g][ni] = 8192 + g * 2048 + (wn * 32 + ni * 16 + lrow) * 32 + quad * 8;

    f32x4 acc[3][4][2] = {};

    for (int k0 = 0; k0 < H_SZ; k0 += 64) {
        __syncthreads();
#pragma unroll
        for (int i = 0; i < 10; ++i)
            gl_lds16(gsrc[i] + k0, &lds[lbase[i]]);
        __syncthreads();
#pragma unroll
        for (int half = 0; half < 2; ++half) {
            f16x8 aa[4], bb[3][2];
#pragma unroll
            for (int mi = 0; mi < 4; ++mi)
                aa[mi] = *(const f16x8*)&lds[half * 4096 + offA[mi]];
#pragma unroll
            for (int g = 0; g < 3; ++g)
#pragma unroll
                for (int ni = 0; ni < 2; ++ni)
                    bb[g][ni] = *(const f16x8*)&lds[half * 6144 + offB[g][ni]];
#pragma unroll
            for (int g = 0; g < 3; ++g)
#pragma unroll
                for (int mi = 0; mi < 4; ++mi)
#pragma unroll
                    for (int ni = 0; ni < 2; ++ni)
                        acc[g][mi][ni] = __builtin_amdgcn_mfma_f32_16x16x32_f16(
                            aa[mi], bb[g][ni], acc[g][mi][ni], 0, 0, 0);
        }
    }

    // -------- fused epilogue: gates, h_next, delta partials --------
#pragma unroll
    for (int mi = 0; mi < 4; ++mi) {
        float p0[4], p1[4];
#pragma unroll
        for (int reg = 0; reg < 4; ++reg) {
            const int b = b0 + wm * 64 + mi * 16 + quad * 4 + reg;
            if (t > 0) {
                p0[reg] = teach[b * (T_SZ * 2) + (t - 1) * 2 + 0];
                p1[reg] = teach[b * (T_SZ * 2) + (t - 1) * 2 + 1];
            } else {
                p0[reg] = 0.f;
                p1[reg] = 0.f;
            }
        }
        float s0[4] = {0.f, 0.f, 0.f, 0.f};
        float s1[4] = {0.f, 0.f, 0.f, 0.f};
#pragma unroll
        for (int ni = 0; ni < 2; ++ni) {
            const int j = j0 + wn * 32 + ni * 16 + lrow;
            const float wr0 = w_ih[(0 * H_SZ + j) * 2 + 0];
            const float wr1 = w_ih[(0 * H_SZ + j) * 2 + 1];
            const float wz0 = w_ih[(1 * H_SZ + j) * 2 + 0];
            const float wz1 = w_ih[(1 * H_SZ + j) * 2 + 1];
            const float wn0 = w_ih[(2 * H_SZ + j) * 2 + 0];
            const float wn1 = w_ih[(2 * H_SZ + j) * 2 + 1];
            const float br = b_ih[0 * H_SZ + j] + b_hh[0 * H_SZ + j];
            const float bz = b_ih[1 * H_SZ + j] + b_hh[1 * H_SZ + j];
            const float bn = b_ih[2 * H_SZ + j];
            const float hbn = b_hh[2 * H_SZ + j];
            const float wo0 = w_out[j], wo1 = w_out[H_SZ + j];
#pragma unroll
            for (int reg = 0; reg < 4; ++reg) {
                const int b = b0 + wm * 64 + mi * 16 + quad * 4 + reg;
                const float hr = acc[0][mi][ni][reg];
                const float hz = acc[1][mi][ni][reg];
                const float hn_ = acc[2][mi][ni][reg] + hbn;
                const float xr = wr0 * p0[reg] + wr1 * p1[reg] + br;
                const float xz = wz0 * p0[reg] + wz1 * p1[reg] + bz;
                const float xn = wn0 * p0[reg] + wn1 * p1[reg] + bn;
                const float r = sigmoidf_(xr + hr);
                const float z = sigmoidf_(xz + hz);
                const float n = tanhf(xn + r * hn_);
                const size_t idx = (size_t)b * H_SZ + j;
                const float hold = (float)hh[idx];
                const float hnew = (1.0f - z) * n + z * hold;
                nhh[idx] = (f16)hnew;
                s0[reg] += hnew * wo0;
                s1[reg] += hnew * wo1;
            }
        }
#pragma unroll
        for (int reg = 0; reg < 4; ++reg) {
#pragma unroll
            for (int m = 1; m < 16; m <<= 1) {
                s0[reg] += __shfl_xor(s0[reg], m);
                s1[reg] += __shfl_xor(s1[reg], m);
            }
            if (lrow == 0) {
                const int b = b0 + wm * 64 + mi * 16 + quad * 4 + reg;
                atomicAdd(&out[b * (T_SZ * 2) + t * 2 + 0], s0[reg]);
                atomicAdd(&out[b * (T_SZ * 2) + t * 2 + 1], s1[reg]);
            }
        }
    }
}

// ---------------------------------------------------------------------------
// pred_deltas += b_out; pred_pos = cumsum
__global__ __launch_bounds__(256) void final_kernel(
        float* __restrict__ out, float* __restrict__ pos,
        const float* __restrict__ b_out) {
    int idx = blockIdx.x * 256 + threadIdx.x;  // b*2 + c
    if (idx >= B_SZ * 2) return;
    int b = idx >> 1, c = idx & 1;
    float bc = b_out[c];
    float acc = 0.0f;
    for (int t = 0; t < T_SZ; ++t) {
        float d = out[b * (T_SZ * 2) + t * 2 + c] + bc;
        out[b * (T_SZ * 2) + t * 2 + c] = d;
        acc += d;
        pos[b * (T_SZ * 2) + t * 2 + c] = acc;
    }
}

// ---------------------------------------------------------------------------
extern "C" void kernel_launch(void* const* d_in, const int* in_sizes, int n_in,
                              void* d_out, int out_size, void* d_ws, size_t ws_size,
                              hipStream_t stream) {
    const float* ev     = (const float*)d_in[0];
    const float* teach  = (const float*)d_in[1];
    const float* w_init = (const float*)d_in[2];
    const float* b_init = (const float*)d_in[3];
    const float* w_ih   = (const float*)d_in[4];
    const float* w_hh   = (const float*)d_in[5];
    const float* b_ih   = (const float*)d_in[6];
    const float* b_hh   = (const float*)d_in[7];
    const float* w_out  = (const float*)d_in[8];
    const float* b_out  = (const float*)d_in[9];

    float* out = (float*)d_out;                  // pred_deltas (B,T,2)
    float* pos = out + (size_t)B_SZ * T_SZ * 2;  // pred_pos    (B,T,2)

    // ws layout (f16 units): hA (4M), hB (4M), w_hh (3M), w_init (1M).
    // ev_f16 (4M) aliases hB (consumed by h0 before hB is first written).
    f16* ws = (f16*)d_ws;
    f16* hA    = ws;
    f16* hB    = hA + (size_t)B_SZ * H_SZ;
    f16* whh   = hB + (size_t)B_SZ * H_SZ;
    f16* winit = whh + (size_t)3 * H_SZ * H_SZ;
    f16* evf   = hB;  // alias

    hipMemsetAsync(out, 0, (size_t)B_SZ * T_SZ * 2 * sizeof(float), stream);

    conv_kernel<<<(3 * H_SZ * H_SZ) / 1024, 256, 0, stream>>>(w_hh, whh, 3 * H_SZ * H_SZ);
    conv_kernel<<<(H_SZ * D_SZ) / 1024, 256, 0, stream>>>(w_init, winit, H_SZ * D_SZ);
    conv_kernel<<<(B_SZ * D_SZ) / 1024, 256, 0, stream>>>(ev, evf, B_SZ * D_SZ);

    dim3 grid(H_SZ / 64, B_SZ / 128);  // (16, 32) = 512 blocks
    h0_kernel<<<grid, 256, 0, stream>>>(evf, winit, b_init, hA);

    f16 *hc = hA, *hn = hB;
    for (int t = 0; t < T_SZ; ++t) {
        step_kernel<<<grid, 256, 0, stream>>>(hc, whh, b_hh, w_ih, b_ih, w_out,
                                              teach, hn, out, t);
        f16* tmp = hc; hc = hn; hn = tmp;
    }
    final_kernel<<<(B_SZ * 2 + 255) / 256, 256, 0, stream>>>(out, pos, b_out);
}